// Round 15
// baseline (111.023 us; speedup 1.0000x reference)
//
#include <hip/hip_runtime.h>

#define B_DIM 8
#define GN_EPS 1e-5f

typedef short s16x8 __attribute__((ext_vector_type(8)));
typedef float f32x4 __attribute__((ext_vector_type(4)));
typedef unsigned int u32x2 __attribute__((ext_vector_type(2)));
typedef s16x8 s16x8_a __attribute__((may_alias));
typedef u32x2 u32x2_a __attribute__((may_alias));

// fp32 -> bf16 bits, round-to-nearest-even
__device__ inline unsigned short f2bf(float f) {
    unsigned u = __builtin_bit_cast(unsigned, f);
    u += 0x7fffu + ((u >> 16) & 1u);
    return (unsigned short)(u >> 16);
}

// pack two fp32 -> two bf16 in one u32 (RNE), low half = lo
__device__ inline unsigned cvtpk(float lo, float hi) {
    unsigned r;
    asm("v_cvt_pk_bf16_f32 %0, %1, %2" : "=v"(r) : "v"(lo), "v"(hi));
    return r;
}

// D = A*B + C, 16x16x32 bf16 (A: row=lane&15,k=(lane>>4)*8+j; B: col=lane&15;
// C/D: col=lane&15,row=(lane>>4)*4+reg). Builtin -> hazard recognizer active.
__device__ inline f32x4 mfma16(s16x8 a, s16x8 b, f32x4 c) {
    return __builtin_amdgcn_mfma_f32_16x16x32_bf16(a, b, c, 0, 0, 0);
}

// async global->LDS, 16B per lane; lds dst must be wave-uniform base
__device__ inline void gload16(const unsigned short* g, unsigned short* l) {
    __builtin_amdgcn_global_load_lds(
        (const __attribute__((address_space(1))) unsigned int*)g,
        (__attribute__((address_space(3))) unsigned int*)l, 16, 0, 0);
}

// NOTE: counted-vmcnt asm is only sound when (a) the kernel has ZERO spill
// traffic (scratch ops count toward vmcnt) and (b) the wait depth covers a
// FULL future tile (vmcnt(4), triple-buffer). Mixed-depth contracts
// (vmcnt(2) over interleaved K/V streams) failed on hardware 3/3 (r9/r10/r13)
// despite sound-on-paper accounting — do not reintroduce.
#define WAIT_VM4() asm volatile("s_waitcnt vmcnt(4)" : : : "memory")
#define WAIT_VM0() asm volatile("s_waitcnt vmcnt(0)" : : : "memory")
#define BAR() __builtin_amdgcn_s_barrier()
// s_barrier is not a compiler memory fence; pin the schedule at it.
#define SFENCE() __builtin_amdgcn_sched_barrier(0)

// swizzled ushort index in a [rows][64] bf16 tile (128B rows): XOR 16B chunks
#define SWZ(r, c) ((r)*64 + ((c) ^ (((r)&7) << 3)))

// ---------------------------------------------------------------------------
// prep: fused {x transpose->bf16} + {w_qkv cvt} + {w_proj cvt}, one launch.
// blocks 0..1023: xT (16 ntile x 8 ctile x 8 b); 1024..1791: wq; 1792..2047: wp
// ---------------------------------------------------------------------------
__global__ __launch_bounds__(256)
void prep_kernel(const float* __restrict__ x, const float* __restrict__ wq,
                 const float* __restrict__ wp, unsigned short* __restrict__ xt,
                 unsigned short* __restrict__ wqb, unsigned short* __restrict__ wpb) {
    const int bid = blockIdx.x, t = threadIdx.x;
    __shared__ float ts[64][65];
    if (bid < 1024) {
        const int ntile = bid & 15, ctile = (bid >> 4) & 7, b = bid >> 7;
        const float* xp = x + ((size_t)b * 512 + ctile * 64) * 1024 + ntile * 64;
        #pragma unroll
        for (int i = 0; i < 16; ++i) {
            int f = i * 256 + t; int c = f >> 6, n = f & 63;
            ts[n][c] = xp[(size_t)c * 1024 + n];
        }
        __syncthreads();
        unsigned short* xo = xt + ((size_t)b * 1024 + ntile * 64) * 512 + ctile * 64;
        #pragma unroll
        for (int i = 0; i < 8; ++i) {
            int f = i * 512 + t * 2; int n = f >> 6, c = f & 63;
            unsigned lo = f2bf(ts[n][c]);
            unsigned hi = f2bf(ts[n][c + 1]);
            *(unsigned int*)&xo[(size_t)n * 512 + c] = lo | (hi << 16);
        }
    } else {
        const float4* src; unsigned short* dst; int idx;
        if (bid < 1792) { idx = (bid - 1024) * 256 + t; src = (const float4*)wq; dst = wqb; }
        else            { idx = (bid - 1792) * 256 + t; src = (const float4*)wp; dst = wpb; }
        float4 v = src[idx];
        ushort4 pk;
        pk.x = f2bf(v.x); pk.y = f2bf(v.y); pk.z = f2bf(v.z); pk.w = f2bf(v.w);
        *(ushort4*)&dst[(size_t)idx * 4] = pk;
    }
}

// ---------------------------------------------------------------------------
// GEMM Y[b][o][n] = sum_c W[o][c]*X[c][n]; A = Wb bf16 [O][512], B from
// Xt bf16 [b][n][512]. 128o x 128n tile, BK=32, 4 waves (2x2 of 64x64).
// K-loop: TRIPLE-buffered LDS, 2-deep prefetch, counted vmcnt(4) + raw
// s_barrier + sched_barrier(0) fence.
// MODE 1 (QKV): LDS-transpose epilogue -> qt/kt [b][h][n][64] (q scaled by
//   0.125*log2e), vt tiled [b][h][mtile][64 d][64 m]; all b64 stores.
// MODE 2 (proj): bf16 out [b][c][n] via same transpose + fused GN stats.
// ---------------------------------------------------------------------------
template<int O_DIM, int MODE>
__global__ __launch_bounds__(256)
void mm_kernel(const unsigned short* __restrict__ Wb,
               const unsigned short* __restrict__ Xt,
               unsigned short* __restrict__ proj_bf,
               unsigned short* __restrict__ qt,
               unsigned short* __restrict__ kt,
               unsigned short* __restrict__ vt,
               float* __restrict__ partial) {
    constexpr int OT = O_DIM / 128;
    const int bi = blockIdx.x;
    const int nt = bi & 7;             // same n-tile -> same XCD (L2 reuse of Xt)
    const int rest = bi >> 3;
    const int ot = rest % OT;
    const int b  = rest / OT;

    const int t = threadIdx.x;
    const int w = t >> 6, lid = t & 63, lr = lid & 15, g4 = lid >> 4;
    const int wr = w >> 1, wc = w & 1;

    // 3 staging bufs (8192 ushorts each: Ws[128][32] | Xs[128][32]);
    // epilogue reuses first 17408 as 4 per-wave 64x68 T tiles.
    __shared__ unsigned short lds[24576];

    const unsigned short* wsrc = Wb + ((size_t)(ot * 128 + w * 32 + (lid >> 2))) * 512 + (lid & 3) * 8;
    const unsigned short* xsrc = Xt + ((size_t)b * 1024 + nt * 128 + w * 32 + (lid >> 2)) * 512 + (lid & 3) * 8;
    const int woff0 = (w * 32) * 32;
    const int woff1 = (w * 32 + 16) * 32;

    const f32x4 Z4 = {0.f, 0.f, 0.f, 0.f};
    f32x4 acc[4][4];
    #pragma unroll
    for (int i = 0; i < 4; ++i)
        #pragma unroll
        for (int j = 0; j < 4; ++j) acc[i][j] = Z4;

    // prologue: stage K-tiles 0 and 1
    #pragma unroll
    for (int p = 0; p < 2; ++p) {
        unsigned short* nb = lds + p * 8192;
        const int k0 = p * 32;
        gload16(wsrc + k0, nb + woff0);
        gload16(wsrc + k0 + 16 * 512, nb + woff1);
        gload16(xsrc + k0, nb + 4096 + woff0);
        gload16(xsrc + k0 + 16 * 512, nb + 4096 + woff1);
    }
    WAIT_VM4(); BAR(); SFENCE();             // tile 0 resident (tile 1 in flight)

    #pragma unroll 1
    for (int it = 0; it < 16; ++it) {
        unsigned short* buf = lds + (it % 3) * 8192;
        if (it <= 13) {                      // 2-deep prefetch
            const int k2 = (it + 2) * 32;
            unsigned short* nb = lds + ((it + 2) % 3) * 8192;
            gload16(wsrc + k2, nb + woff0);
            gload16(wsrc + k2 + 16 * 512, nb + woff1);
            gload16(xsrc + k2, nb + 4096 + woff0);
            gload16(xsrc + k2 + 16 * 512, nb + 4096 + woff1);
        }
        s16x8 av[4], bv[4];
        #pragma unroll
        for (int mi = 0; mi < 4; ++mi)
            av[mi] = *(const s16x8*)&buf[(wr * 64 + mi * 16 + lr) * 32 + g4 * 8];
        #pragma unroll
        for (int nj = 0; nj < 4; ++nj)
            bv[nj] = *(const s16x8*)&buf[4096 + (wc * 64 + nj * 16 + lr) * 32 + g4 * 8];
        #pragma unroll
        for (int mi = 0; mi < 4; ++mi)
            #pragma unroll
            for (int nj = 0; nj < 4; ++nj)
                acc[mi][nj] = mfma16(av[mi], bv[nj], acc[mi][nj]);
        if (it <= 13)      { WAIT_VM4(); BAR(); SFENCE(); }   // next tile resident
        else if (it == 14) { WAIT_VM0(); BAR(); SFENCE(); }   // last tile resident
    }

    if (MODE == 2) {
        // fused GroupNorm partial stats over this wave's 64x64 quadrant
        // (entirely in group g = ot*2 + wr) — register-only, pre-barrier.
        float s1 = 0.f, s2 = 0.f;
        #pragma unroll
        for (int mi = 0; mi < 4; ++mi)
            #pragma unroll
            for (int nj = 0; nj < 4; ++nj)
                #pragma unroll
                for (int r = 0; r < 4; ++r) {
                    float v = acc[mi][nj][r];
                    s1 += v;
                    s2 += v * v;
                }
        #pragma unroll
        for (int off = 1; off <= 32; off <<= 1) {
            s1 += __shfl_xor(s1, off);
            s2 += __shfl_xor(s2, off);
        }
        if (lid == 0) {
            float2* pp = (float2*)partial + ((size_t)(b * 8 + ot * 2 + wr) * 16)
                         + nt * 2 + wc;
            *pp = make_float2(s1, s2);
        }
    }

    __syncthreads();                          // all waves done with staging LDS
    unsigned short* T = lds + w * 4352;       // per-wave 64x68 ushort
    const int obase = ot * 128 + wr * 64;
    const int j16 = lid & 15, r4 = lid >> 4;
    const size_t n0w = (size_t)nt * 128 + wc * 64;

    if (MODE == 1) {
        const int s = obase >> 9;             // 0=q 1=k 2=v
        const int h = (obase >> 6) & 7;
        const float scl = (s == 0) ? 0.18033688f : 1.0f;   // 0.125 * log2(e)
        #pragma unroll
        for (int mi = 0; mi < 4; ++mi)
            #pragma unroll
            for (int nj = 0; nj < 4; ++nj)
                #pragma unroll
                for (int r = 0; r < 4; ++r) {
                    int ol = mi * 16 + g4 * 4 + r, nl = nj * 16 + lr;
                    unsigned short v = f2bf(acc[mi][nj][r] * scl);
                    T[(s < 2) ? (nl * 68 + ol) : (ol * 68 + nl)] = v;
                }
        // q/k: [n][64 d]; vt tiled: [mtile][64 d][64 m] -> same base formula
        unsigned short* obuf = ((s == 0) ? qt : (s == 1) ? kt : vt)
                               + ((size_t)(b * 8 + h) * 1024 + n0w) * 64;
        #pragma unroll
        for (int p = 0; p < 16; ++p) {
            int rw = p * 4 + r4;
            u32x2 v = *(const u32x2_a*)&T[rw * 68 + 4 * j16];
            *(u32x2_a*)(obuf + rw * 64 + 4 * j16) = v;
        }
    } else {
        #pragma unroll
        for (int mi = 0; mi < 4; ++mi)
            #pragma unroll
            for (int nj = 0; nj < 4; ++nj)
                #pragma unroll
                for (int r = 0; r < 4; ++r)
                    T[(mi * 16 + g4 * 4 + r) * 68 + nj * 16 + lr] = f2bf(acc[mi][nj][r]);
        #pragma unroll
        for (int p = 0; p < 16; ++p) {
            int rw = p * 4 + r4;
            u32x2 v = *(const u32x2_a*)&T[rw * 68 + 4 * j16];
            *(u32x2_a*)(proj_bf + ((size_t)(b * 512 + obase + rw)) * 1024
                        + nt * 128 + wc * 64 + 4 * j16) = v;
        }
    }
}

// ---------------------------------------------------------------------------
// Flash attention, bf16 MFMA, static-max softmax — BARRIER-FREE version.
// Block = (b,h,128-q-tile), 4 waves x 32 q-rows, grid 512. Q in registers.
// K/V for one head are L2-resident (256KB, XCD-pinned by h=bi&7), so K/V
// fragments are read DIRECTLY from global as per-lane b128 loads (kt[m][d]
// and tiled vt[d][m] give 16B-contiguous MFMA fragments — byte-identical
// data to the old staged path). No LDS staging -> no barriers, no vmcnt
// contracts, no inter-wave communication at all (P LDS rows are wave-
// private stripes; same-wave DS ops complete in order). The round-8..13
// hazard class is structurally impossible here; spills merely cost speed.
// ---------------------------------------------------------------------------
__global__ __launch_bounds__(256)
void attn_kernel(const unsigned short* __restrict__ qt,
                 const unsigned short* __restrict__ kt,
                 const unsigned short* __restrict__ vt,
                 unsigned short* __restrict__ aout) {
    const int bi = blockIdx.x;
    const int h = bi & 7;               // all q-tiles of a head -> same XCD
    const int qtile = (bi >> 3) & 7;
    const int b = bi >> 6;

    const int t = threadIdx.x;
    const int w = t >> 6, lid = t & 63, lr = lid & 15, g4 = lid >> 4;

    __shared__ unsigned short Ps[8192];   // [128][64] swz; rows w*32.. wave-private

    const unsigned short* qbh = qt + ((size_t)b * 8 + h) * 65536;
    const unsigned short* kbh = kt + ((size_t)b * 8 + h) * 65536;
    const unsigned short* vbh = vt + ((size_t)b * 8 + h) * 65536;

    // ---- Q fragments straight into registers (B-operand: col=n, k=d)
    s16x8 qa[2][2];
    #pragma unroll
    for (int mi = 0; mi < 2; ++mi)
        #pragma unroll
        for (int ks = 0; ks < 2; ++ks)
            qa[mi][ks] = *(const s16x8*)(qbh +
                (size_t)(qtile * 128 + w * 32 + mi * 16 + lr) * 64 + ks * 32 + g4 * 8);

    const f32x4 Z4 = {0.f, 0.f, 0.f, 0.f};
    f32x4 acc_o[2][4];
    float l_run[2] = {0.f, 0.f};
    #pragma unroll
    for (int mi = 0; mi < 2; ++mi)
        #pragma unroll
        for (int di = 0; di < 4; ++di) acc_o[mi][di] = Z4;

    #pragma unroll 1
    for (int it = 0; it < 16; ++it) {
        const unsigned short* kc = kbh + it * 4096;   // [64 m][64 d]
        const unsigned short* vc = vbh + it * 4096;   // tiled [64 d][64 m]

        // ---- S^T: sc[mi][mj] = mfma(K, Q) -> row=m=mj*16+g4*4+r, col=n
        f32x4 sc[2][4];
        #pragma unroll
        for (int mi = 0; mi < 2; ++mi)
            #pragma unroll
            for (int mj = 0; mj < 4; ++mj) sc[mi][mj] = Z4;
        #pragma unroll
        for (int ks = 0; ks < 2; ++ks) {
            s16x8 kb[4];
            #pragma unroll
            for (int mj = 0; mj < 4; ++mj)
                kb[mj] = *(const s16x8_a*)(kc + (mj * 16 + lr) * 64 + ks * 32 + g4 * 8);
            #pragma unroll
            for (int mi = 0; mi < 2; ++mi)
                #pragma unroll
                for (int mj = 0; mj < 4; ++mj)
                    sc[mi][mj] = mfma16(kb[mj], qa[mi][ks], sc[mi][mj]);
        }

        // ---- p = exp2(s) (log2e pre-folded), accumulate l, pack, store
        #pragma unroll
        for (int mi = 0; mi < 2; ++mi) {
            #pragma unroll
            for (int mj = 0; mj < 4; ++mj) {
                float p0 = __builtin_amdgcn_exp2f(sc[mi][mj][0]);
                float p1 = __builtin_amdgcn_exp2f(sc[mi][mj][1]);
                float p2 = __builtin_amdgcn_exp2f(sc[mi][mj][2]);
                float p3 = __builtin_amdgcn_exp2f(sc[mi][mj][3]);
                l_run[mi] += (p0 + p1) + (p2 + p3);
                u32x2 pk;
                pk.x = cvtpk(p0, p1);
                pk.y = cvtpk(p2, p3);
                *(u32x2_a*)&Ps[SWZ(w * 32 + mi * 16 + lr, mj * 16 + g4 * 4)] = pk;
            }
        }

        // ---- V fragments direct from L2 (B-operand: col=d, k=m-run)
        s16x8 vb[2][4];
        #pragma unroll
        for (int ks = 0; ks < 2; ++ks)
            #pragma unroll
            for (int di = 0; di < 4; ++di)
                vb[ks][di] = *(const s16x8_a*)(vc + (di * 16 + lr) * 64 + ks * 32 + g4 * 8);

        // ---- PV: acc_o[mi][di] += P[32n x 64m] * V^T[64m x 64d]
        #pragma unroll
        for (int ks = 0; ks < 2; ++ks) {
            s16x8 pa[2];
            #pragma unroll
            for (int mi = 0; mi < 2; ++mi)
                pa[mi] = *(const s16x8_a*)&Ps[SWZ(w * 32 + mi * 16 + lr, ks * 32 + g4 * 8)];
            #pragma unroll
            for (int mi = 0; mi < 2; ++mi)
                #pragma unroll
                for (int di = 0; di < 4; ++di)
                    acc_o[mi][di] = mfma16(pa[mi], vb[ks][di], acc_o[mi][di]);
        }
    }

    // ---- reduce l across g4 groups (lane holds quarter-sum for its n col)
    #pragma unroll
    for (int mi = 0; mi < 2; ++mi) {
        float l = l_run[mi];
        l += __shfl_xor(l, 16);
        l += __shfl_xor(l, 32);
        l_run[mi] = 1.f / l;
    }
    // ---- normalize + write aout[b][n][c] bf16 (acc rows n = g4*4+r)
    #pragma unroll
    for (int mi = 0; mi < 2; ++mi) {
        float inv[4];
        #pragma unroll
        for (int r = 0; r < 4; ++r)
            inv[r] = __shfl(l_run[mi], g4 * 4 + r);   // src lane's lr == g4*4+r
        #pragma unroll
        for (int di = 0; di < 4; ++di)
            #pragma unroll
            for (int r = 0; r < 4; ++r) {
                int n = qtile * 128 + w * 32 + mi * 16 + g4 * 4 + r;
                int c = h * 64 + di * 16 + lr;
                aout[((size_t)b * 1024 + n) * 512 + c] = f2bf(acc_o[mi][di][r] * inv[r]);
            }
    }
}

// ---------------------------------------------------------------------------
// GroupNorm apply + affine + residual: reads bf16 proj + fp32 x, writes fp32
// out. Stats from 16 float2 partials per (b,g) (proj GEMM epilogue).
// ---------------------------------------------------------------------------
__global__ __launch_bounds__(256)
void gn_apply_kernel(const unsigned short* __restrict__ pb,
                     const float* __restrict__ partial, const float* __restrict__ x,
                     const float* __restrict__ gamma, const float* __restrict__ beta,
                     float* __restrict__ out) {
    const int qtr = blockIdx.x;   // 16: 4 channels each
    const int g = blockIdx.y;
    const int b = blockIdx.z;
    const int t = threadIdx.x;
    const float2* pp = (const float2*)partial + (size_t)(b * 8 + g) * 16;
    float sum = 0.f, sq = 0.f;
    #pragma unroll
    for (int s = 0; s < 16; ++s) { sum += pp[s].x; sq += pp[s].y; }
    const float mean = sum * (1.f / 65536.f);
    const float var  = sq * (1.f / 65536.f) - mean * mean;
    const float rstd = rsqrtf(var + GN_EPS);
    #pragma unroll
    for (int j = 0; j < 2; ++j) {
        const int c = g * 64 + qtr * 4 + j * 2 + (t >> 7);
        const float gm = gamma[c] * rstd, bt = beta[c];
        const size_t base = ((size_t)b * 512 + c) * 1024 + (t & 127) * 8;
        s16x8 pv = *(const s16x8_a*)(pb + base);
        float4 xa = *(const float4*)(x + base);
        float4 xb = *(const float4*)(x + base + 4);
        float4 ra, rb;
        ra.x = (__builtin_bit_cast(float, ((unsigned)(unsigned short)pv[0]) << 16) - mean) * gm + bt + xa.x;
        ra.y = (__builtin_bit_cast(float, ((unsigned)(unsigned short)pv[1]) << 16) - mean) * gm + bt + xa.y;
        ra.z = (__builtin_bit_cast(float, ((unsigned)(unsigned short)pv[2]) << 16) - mean) * gm + bt + xa.z;
        ra.w = (__builtin_bit_cast(float, ((unsigned)(unsigned short)pv[3]) << 16) - mean) * gm + bt + xa.w;
        rb.x = (__builtin_bit_cast(float, ((unsigned)(unsigned short)pv[4]) << 16) - mean) * gm + bt + xb.x;
        rb.y = (__builtin_bit_cast(float, ((unsigned)(unsigned short)pv[5]) << 16) - mean) * gm + bt + xb.y;
        rb.z = (__builtin_bit_cast(float, ((unsigned)(unsigned short)pv[6]) << 16) - mean) * gm + bt + xb.z;
        rb.w = (__builtin_bit_cast(float, ((unsigned)(unsigned short)pv[7]) << 16) - mean) * gm + bt + xb.w;
        *(float4*)(out + base) = ra;
        *(float4*)(out + base + 4) = rb;
    }
}

// ---------------------------------------------------------------------------
extern "C" void kernel_launch(void* const* d_in, const int* in_sizes, int n_in,
                              void* d_out, int out_size, void* d_ws, size_t ws_size,
                              hipStream_t stream) {
    (void)in_sizes; (void)n_in; (void)out_size; (void)ws_size;
    const float* x      = (const float*)d_in[0];
    const float* w_qkv  = (const float*)d_in[1];
    const float* w_proj = (const float*)d_in[2];
    const float* gamma  = (const float*)d_in[3];
    const float* beta   = (const float*)d_in[4];
    float* out = (float*)d_out;

    // workspace layout (ushort units), ~53 MB of 256 MB
    unsigned short* qtb  = (unsigned short*)d_ws;         // [8][8][1024][64]
    unsigned short* ktb  = qtb  + 4194304;                // [8][8][1024][64]
    unsigned short* vtb  = ktb  + 4194304;                // [8][8][16][64][64] tiled
    unsigned short* aoutb= vtb  + 4194304;                // [8][1024][512]
    unsigned short* xtb  = aoutb+ 4194304;                // [8][1024][512]
    unsigned short* pbf  = xtb  + 4194304;                // [8][512][1024] bf16 proj
    unsigned short* wqb  = pbf  + 4194304;                // [1536][512]
    unsigned short* wpb  = wqb  + 786432;                 // [512][512]
    float* partial = (float*)(wpb + 262144);              // [64][16] float2

    // 1) fused prep: xT + weight converts
    prep_kernel<<<2048, 256, 0, stream>>>(x, w_qkv, w_proj, xtb, wqb, wpb);
    // 2) QKV GEMM -> qt/kt (q scaled for exp2) + tiled vt
    mm_kernel<1536, 1><<<768, 256, 0, stream>>>(wqb, xtb, nullptr, qtb, ktb, vtb, nullptr);
    // 3) attention (barrier-free, K/V direct from L2) -> aout[b][n][c] bf16
    attn_kernel<<<512, 256, 0, stream>>>(qtb, ktb, vtb, aoutb);
    // 4) proj GEMM -> bf16 [b][c][n] + fused GN partial stats
    mm_kernel<512, 2><<<256, 256, 0, stream>>>(wpb, aoutb, pbf, nullptr, nullptr, nullptr, partial);
    // 5) GroupNorm apply (+affine +residual) -> fp32 out
    gn_apply_kernel<<<dim3(16, 8, B_DIM), 256, 0, stream>>>(pbf, partial, x, gamma, beta, out);
}

// Round 16
// 77.829 us; speedup vs baseline: 1.4265x; 1.4265x over previous
//
#include <hip/hip_runtime.h>

#define B_DIM 8
#define GN_EPS 1e-5f

typedef short s16x8 __attribute__((ext_vector_type(8)));
typedef float f32x4 __attribute__((ext_vector_type(4)));
typedef unsigned int u32x2 __attribute__((ext_vector_type(2)));
typedef s16x8 s16x8_a __attribute__((may_alias));
typedef u32x2 u32x2_a __attribute__((may_alias));

// fp32 -> bf16 bits, round-to-nearest-even
__device__ inline unsigned short f2bf(float f) {
    unsigned u = __builtin_bit_cast(unsigned, f);
    u += 0x7fffu + ((u >> 16) & 1u);
    return (unsigned short)(u >> 16);
}

// pack two fp32 -> two bf16 in one u32 (RNE), low half = lo
__device__ inline unsigned cvtpk(float lo, float hi) {
    unsigned r;
    asm("v_cvt_pk_bf16_f32 %0, %1, %2" : "=v"(r) : "v"(lo), "v"(hi));
    return r;
}

// D = A*B + C, 16x16x32 bf16 (A: row=lane&15,k=(lane>>4)*8+j; B: col=lane&15;
// C/D: col=lane&15,row=(lane>>4)*4+reg). Builtin -> hazard recognizer active.
__device__ inline f32x4 mfma16(s16x8 a, s16x8 b, f32x4 c) {
    return __builtin_amdgcn_mfma_f32_16x16x32_bf16(a, b, c, 0, 0, 0);
}

// async global->LDS, 16B per lane; lds dst must be wave-uniform base
__device__ inline void gload16(const unsigned short* g, unsigned short* l) {
    __builtin_amdgcn_global_load_lds(
        (const __attribute__((address_space(1))) unsigned int*)g,
        (__attribute__((address_space(3))) unsigned int*)l, 16, 0, 0);
}

// NOTE: counted-vmcnt asm is only sound when (a) the kernel has ZERO spill
// traffic (scratch ops count toward vmcnt) and (b) the wait depth covers a
// FULL future tile (vmcnt(4), triple-buffer). Mixed-depth contracts
// (vmcnt(2) over interleaved K/V streams) failed on hardware 3/3 (r9/r10/r13).
// Per-lane global K/V reads (no staging) passed but were 3.4x SLOWER (r15:
// L2 latency exposure, no async queue depth). The staged vmcnt(4) pipeline
// below is the only fast AND correct schedule found — do not deviate.
#define WAIT_VM4() asm volatile("s_waitcnt vmcnt(4)" : : : "memory")
#define WAIT_VM0() asm volatile("s_waitcnt vmcnt(0)" : : : "memory")
#define BAR() __builtin_amdgcn_s_barrier()
// s_barrier is not a compiler memory fence; pin the schedule at it.
#define SFENCE() __builtin_amdgcn_sched_barrier(0)

// swizzled ushort index in a [rows][64] bf16 tile (128B rows): XOR 16B chunks
#define SWZ(r, c) ((r)*64 + ((c) ^ (((r)&7) << 3)))

// ---------------------------------------------------------------------------
// prep: fused {x transpose->bf16} + {w_qkv cvt} + {w_proj cvt}, one launch.
// blocks 0..1023: xT (16 ntile x 8 ctile x 8 b); 1024..1791: wq; 1792..2047: wp
// ---------------------------------------------------------------------------
__global__ __launch_bounds__(256)
void prep_kernel(const float* __restrict__ x, const float* __restrict__ wq,
                 const float* __restrict__ wp, unsigned short* __restrict__ xt,
                 unsigned short* __restrict__ wqb, unsigned short* __restrict__ wpb) {
    const int bid = blockIdx.x, t = threadIdx.x;
    __shared__ float ts[64][65];
    if (bid < 1024) {
        const int ntile = bid & 15, ctile = (bid >> 4) & 7, b = bid >> 7;
        const float* xp = x + ((size_t)b * 512 + ctile * 64) * 1024 + ntile * 64;
        #pragma unroll
        for (int i = 0; i < 16; ++i) {
            int f = i * 256 + t; int c = f >> 6, n = f & 63;
            ts[n][c] = xp[(size_t)c * 1024 + n];
        }
        __syncthreads();
        unsigned short* xo = xt + ((size_t)b * 1024 + ntile * 64) * 512 + ctile * 64;
        #pragma unroll
        for (int i = 0; i < 8; ++i) {
            int f = i * 512 + t * 2; int n = f >> 6, c = f & 63;
            unsigned lo = f2bf(ts[n][c]);
            unsigned hi = f2bf(ts[n][c + 1]);
            *(unsigned int*)&xo[(size_t)n * 512 + c] = lo | (hi << 16);
        }
    } else {
        const float4* src; unsigned short* dst; int idx;
        if (bid < 1792) { idx = (bid - 1024) * 256 + t; src = (const float4*)wq; dst = wqb; }
        else            { idx = (bid - 1792) * 256 + t; src = (const float4*)wp; dst = wpb; }
        float4 v = src[idx];
        ushort4 pk;
        pk.x = f2bf(v.x); pk.y = f2bf(v.y); pk.z = f2bf(v.z); pk.w = f2bf(v.w);
        *(ushort4*)&dst[(size_t)idx * 4] = pk;
    }
}

// ---------------------------------------------------------------------------
// GEMM Y[b][o][n] = sum_c W[o][c]*X[c][n]; A = Wb bf16 [O][512], B from
// Xt bf16 [b][n][512]. 128o x 128n tile, BK=32, 4 waves (2x2 of 64x64).
// K-loop: TRIPLE-buffered LDS, 2-deep prefetch, counted vmcnt(4) + raw
// s_barrier + sched_barrier(0) fence.
// MODE 1 (QKV): LDS-transpose epilogue -> qt/kt [b][h][n][64] (q scaled by
//   0.125*log2e), vt tiled [b][h][mtile][64 d][64 m]; all b64 stores.
// MODE 2 (proj): bf16 out [b][c][n] via same transpose + fused GN stats.
// ---------------------------------------------------------------------------
template<int O_DIM, int MODE>
__global__ __launch_bounds__(256)
void mm_kernel(const unsigned short* __restrict__ Wb,
               const unsigned short* __restrict__ Xt,
               unsigned short* __restrict__ proj_bf,
               unsigned short* __restrict__ qt,
               unsigned short* __restrict__ kt,
               unsigned short* __restrict__ vt,
               float* __restrict__ partial) {
    constexpr int OT = O_DIM / 128;
    const int bi = blockIdx.x;
    const int nt = bi & 7;             // same n-tile -> same XCD (L2 reuse of Xt)
    const int rest = bi >> 3;
    const int ot = rest % OT;
    const int b  = rest / OT;

    const int t = threadIdx.x;
    const int w = t >> 6, lid = t & 63, lr = lid & 15, g4 = lid >> 4;
    const int wr = w >> 1, wc = w & 1;

    // 3 staging bufs (8192 ushorts each: Ws[128][32] | Xs[128][32]);
    // epilogue reuses first 17408 as 4 per-wave 64x68 T tiles.
    __shared__ unsigned short lds[24576];

    const unsigned short* wsrc = Wb + ((size_t)(ot * 128 + w * 32 + (lid >> 2))) * 512 + (lid & 3) * 8;
    const unsigned short* xsrc = Xt + ((size_t)b * 1024 + nt * 128 + w * 32 + (lid >> 2)) * 512 + (lid & 3) * 8;
    const int woff0 = (w * 32) * 32;
    const int woff1 = (w * 32 + 16) * 32;

    const f32x4 Z4 = {0.f, 0.f, 0.f, 0.f};
    f32x4 acc[4][4];
    #pragma unroll
    for (int i = 0; i < 4; ++i)
        #pragma unroll
        for (int j = 0; j < 4; ++j) acc[i][j] = Z4;

    // prologue: stage K-tiles 0 and 1
    #pragma unroll
    for (int p = 0; p < 2; ++p) {
        unsigned short* nb = lds + p * 8192;
        const int k0 = p * 32;
        gload16(wsrc + k0, nb + woff0);
        gload16(wsrc + k0 + 16 * 512, nb + woff1);
        gload16(xsrc + k0, nb + 4096 + woff0);
        gload16(xsrc + k0 + 16 * 512, nb + 4096 + woff1);
    }
    WAIT_VM4(); BAR(); SFENCE();             // tile 0 resident (tile 1 in flight)

    #pragma unroll 1
    for (int it = 0; it < 16; ++it) {
        unsigned short* buf = lds + (it % 3) * 8192;
        if (it <= 13) {                      // 2-deep prefetch
            const int k2 = (it + 2) * 32;
            unsigned short* nb = lds + ((it + 2) % 3) * 8192;
            gload16(wsrc + k2, nb + woff0);
            gload16(wsrc + k2 + 16 * 512, nb + woff1);
            gload16(xsrc + k2, nb + 4096 + woff0);
            gload16(xsrc + k2 + 16 * 512, nb + 4096 + woff1);
        }
        s16x8 av[4], bv[4];
        #pragma unroll
        for (int mi = 0; mi < 4; ++mi)
            av[mi] = *(const s16x8*)&buf[(wr * 64 + mi * 16 + lr) * 32 + g4 * 8];
        #pragma unroll
        for (int nj = 0; nj < 4; ++nj)
            bv[nj] = *(const s16x8*)&buf[4096 + (wc * 64 + nj * 16 + lr) * 32 + g4 * 8];
        #pragma unroll
        for (int mi = 0; mi < 4; ++mi)
            #pragma unroll
            for (int nj = 0; nj < 4; ++nj)
                acc[mi][nj] = mfma16(av[mi], bv[nj], acc[mi][nj]);
        if (it <= 13)      { WAIT_VM4(); BAR(); SFENCE(); }   // next tile resident
        else if (it == 14) { WAIT_VM0(); BAR(); SFENCE(); }   // last tile resident
    }

    if (MODE == 2) {
        // fused GroupNorm partial stats over this wave's 64x64 quadrant
        // (entirely in group g = ot*2 + wr) — register-only, pre-barrier.
        float s1 = 0.f, s2 = 0.f;
        #pragma unroll
        for (int mi = 0; mi < 4; ++mi)
            #pragma unroll
            for (int nj = 0; nj < 4; ++nj)
                #pragma unroll
                for (int r = 0; r < 4; ++r) {
                    float v = acc[mi][nj][r];
                    s1 += v;
                    s2 += v * v;
                }
        #pragma unroll
        for (int off = 1; off <= 32; off <<= 1) {
            s1 += __shfl_xor(s1, off);
            s2 += __shfl_xor(s2, off);
        }
        if (lid == 0) {
            float2* pp = (float2*)partial + ((size_t)(b * 8 + ot * 2 + wr) * 16)
                         + nt * 2 + wc;
            *pp = make_float2(s1, s2);
        }
    }

    __syncthreads();                          // all waves done with staging LDS
    unsigned short* T = lds + w * 4352;       // per-wave 64x68 ushort
    const int obase = ot * 128 + wr * 64;
    const int j16 = lid & 15, r4 = lid >> 4;
    const size_t n0w = (size_t)nt * 128 + wc * 64;

    if (MODE == 1) {
        const int s = obase >> 9;             // 0=q 1=k 2=v
        const int h = (obase >> 6) & 7;
        const float scl = (s == 0) ? 0.18033688f : 1.0f;   // 0.125 * log2(e)
        #pragma unroll
        for (int mi = 0; mi < 4; ++mi)
            #pragma unroll
            for (int nj = 0; nj < 4; ++nj)
                #pragma unroll
                for (int r = 0; r < 4; ++r) {
                    int ol = mi * 16 + g4 * 4 + r, nl = nj * 16 + lr;
                    unsigned short v = f2bf(acc[mi][nj][r] * scl);
                    T[(s < 2) ? (nl * 68 + ol) : (ol * 68 + nl)] = v;
                }
        // q/k: [n][64 d]; vt tiled: [mtile][64 d][64 m] -> same base formula
        unsigned short* obuf = ((s == 0) ? qt : (s == 1) ? kt : vt)
                               + ((size_t)(b * 8 + h) * 1024 + n0w) * 64;
        #pragma unroll
        for (int p = 0; p < 16; ++p) {
            int rw = p * 4 + r4;
            u32x2 v = *(const u32x2_a*)&T[rw * 68 + 4 * j16];
            *(u32x2_a*)(obuf + rw * 64 + 4 * j16) = v;
        }
    } else {
        #pragma unroll
        for (int mi = 0; mi < 4; ++mi)
            #pragma unroll
            for (int nj = 0; nj < 4; ++nj)
                #pragma unroll
                for (int r = 0; r < 4; ++r)
                    T[(mi * 16 + g4 * 4 + r) * 68 + nj * 16 + lr] = f2bf(acc[mi][nj][r]);
        #pragma unroll
        for (int p = 0; p < 16; ++p) {
            int rw = p * 4 + r4;
            u32x2 v = *(const u32x2_a*)&T[rw * 68 + 4 * j16];
            *(u32x2_a*)(proj_bf + ((size_t)(b * 512 + obase + rw)) * 1024
                        + nt * 128 + wc * 64 + 4 * j16) = v;
        }
    }
}

// ---------------------------------------------------------------------------
// Flash attention, bf16 MFMA, static-max softmax. Block = (b,h,128-q-tile),
// 4 waves x 32 q-rows, grid 512. Q in registers. K/V TRIPLE-buffered in LDS
// with 2-deep prefetch + counted vmcnt(4) + raw barrier + sched fence.
// vt is tiled [mtile][64 d][64 m] -> every gload is one contiguous 1KB.
// Swapped QK^T -> packed cvt_pk b64 P-stores; l reduced once at the end.
// The ONLY fast+correct pipeline found (passes r7/r11/r12/r14; L2-direct
// r15 was 3.4x slower; all sync deviations failed). Round 16 delta:
// s_setprio(1/0) around MFMA clusters only (hint, no dataflow change;
// exonerated from all failures — r8's was the bpermute bug).
// ---------------------------------------------------------------------------
__global__ __launch_bounds__(256)
void attn_kernel(const unsigned short* __restrict__ qt,
                 const unsigned short* __restrict__ kt,
                 const unsigned short* __restrict__ vt,
                 unsigned short* __restrict__ aout) {
    const int bi = blockIdx.x;
    const int h = bi & 7;               // all q-tiles of a head -> same XCD
    const int qtile = (bi >> 3) & 7;
    const int b = bi >> 6;

    const int t = threadIdx.x;
    const int w = t >> 6, lid = t & 63, lr = lid & 15, g4 = lid >> 4;
    const int rr = lid >> 3, cc = lid & 7;
    const int csw = (cc ^ rr) << 3;     // source pre-swizzle (ushort units)

    // K[3][4096] | V[3][4096] @12288 | P[128][64] @24576   (64KB)
    __shared__ unsigned short lds[32768];
    unsigned short* Ps = lds + 24576;

    const unsigned short* qbh = qt + ((size_t)b * 8 + h) * 65536;
    const unsigned short* kbh = kt + ((size_t)b * 8 + h) * 65536;
    const unsigned short* vbh = vt + ((size_t)b * 8 + h) * 65536;

    // ---- Q fragments straight into registers (B-operand: col=n, k=d)
    s16x8 qa[2][2];
    #pragma unroll
    for (int mi = 0; mi < 2; ++mi)
        #pragma unroll
        for (int ks = 0; ks < 2; ++ks)
            qa[mi][ks] = *(const s16x8*)(qbh +
                (size_t)(qtile * 128 + w * 32 + mi * 16 + lr) * 64 + ks * 32 + g4 * 8);

    // ---- prologue: stage tiles 0,1 (K and tiled-V share the address form)
    #pragma unroll
    for (int p = 0; p < 2; ++p) {
        unsigned short* Kd = lds + p * 4096;
        unsigned short* Vd = lds + 12288 + p * 4096;
        const int m = p * 64;
        #pragma unroll
        for (int i2 = 0; i2 < 2; ++i2) {
            gload16(kbh + (size_t)(m + w * 16 + i2 * 8 + rr) * 64 + csw,
                    Kd + (w * 16 + i2 * 8) * 64);
            gload16(vbh + (size_t)(m + w * 16 + i2 * 8 + rr) * 64 + csw,
                    Vd + (w * 16 + i2 * 8) * 64);
        }
    }
    WAIT_VM4(); BAR(); SFENCE();             // tile 0 resident

    const f32x4 Z4 = {0.f, 0.f, 0.f, 0.f};
    f32x4 acc_o[2][4];
    float l_run[2] = {0.f, 0.f};
    #pragma unroll
    for (int mi = 0; mi < 2; ++mi)
        #pragma unroll
        for (int di = 0; di < 4; ++di) acc_o[mi][di] = Z4;

    #pragma unroll 1
    for (int it = 0; it < 16; ++it) {
        unsigned short* Kc = lds + (it % 3) * 4096;
        unsigned short* Vc = lds + 12288 + (it % 3) * 4096;

        if (it <= 13) {                      // 2-deep prefetch
            const int m2 = (it + 2) * 64;
            unsigned short* Kd = lds + ((it + 2) % 3) * 4096;
            unsigned short* Vd = lds + 12288 + ((it + 2) % 3) * 4096;
            #pragma unroll
            for (int i2 = 0; i2 < 2; ++i2) {
                gload16(kbh + (size_t)(m2 + w * 16 + i2 * 8 + rr) * 64 + csw,
                        Kd + (w * 16 + i2 * 8) * 64);
                gload16(vbh + (size_t)(m2 + w * 16 + i2 * 8 + rr) * 64 + csw,
                        Vd + (w * 16 + i2 * 8) * 64);
            }
        }

        // ---- S^T: sc[mi][mj] = mfma(K, Q) -> row=m=mj*16+g4*4+r, col=n
        f32x4 sc[2][4];
        #pragma unroll
        for (int mi = 0; mi < 2; ++mi)
            #pragma unroll
            for (int mj = 0; mj < 4; ++mj) sc[mi][mj] = Z4;
        #pragma unroll
        for (int ks = 0; ks < 2; ++ks) {
            s16x8 kb[4];
            #pragma unroll
            for (int mj = 0; mj < 4; ++mj)
                kb[mj] = *(const s16x8*)&Kc[SWZ(mj * 16 + lr, ks * 32 + g4 * 8)];
            __builtin_amdgcn_s_setprio(1);
            #pragma unroll
            for (int mi = 0; mi < 2; ++mi)
                #pragma unroll
                for (int mj = 0; mj < 4; ++mj)
                    sc[mi][mj] = mfma16(kb[mj], qa[mi][ks], sc[mi][mj]);
            __builtin_amdgcn_s_setprio(0);
        }

        // ---- p = exp2(s) (log2e pre-folded), accumulate l, pack, store
        #pragma unroll
        for (int mi = 0; mi < 2; ++mi) {
            #pragma unroll
            for (int mj = 0; mj < 4; ++mj) {
                float p0 = __builtin_amdgcn_exp2f(sc[mi][mj][0]);
                float p1 = __builtin_amdgcn_exp2f(sc[mi][mj][1]);
                float p2 = __builtin_amdgcn_exp2f(sc[mi][mj][2]);
                float p3 = __builtin_amdgcn_exp2f(sc[mi][mj][3]);
                l_run[mi] += (p0 + p1) + (p2 + p3);
                u32x2 pk;
                pk.x = cvtpk(p0, p1);
                pk.y = cvtpk(p2, p3);
                *(u32x2_a*)&Ps[SWZ(w * 32 + mi * 16 + lr, mj * 16 + g4 * 4)] = pk;
            }
        }

        // ---- V fragments once per iter (register-resident across mi)
        s16x8 vb[2][4];
        #pragma unroll
        for (int ks = 0; ks < 2; ++ks)
            #pragma unroll
            for (int di = 0; di < 4; ++di)
                vb[ks][di] = *(const s16x8*)&Vc[SWZ(di * 16 + lr, ks * 32 + g4 * 8)];

        // ---- PV: acc_o[mi][di] += P[32n x 64m] * V^T[64m x 64d]
        #pragma unroll
        for (int ks = 0; ks < 2; ++ks) {
            s16x8 pa[2];
            #pragma unroll
            for (int mi = 0; mi < 2; ++mi)
                pa[mi] = *(const s16x8_a*)&Ps[SWZ(w * 32 + mi * 16 + lr, ks * 32 + g4 * 8)];
            __builtin_amdgcn_s_setprio(1);
            #pragma unroll
            for (int mi = 0; mi < 2; ++mi)
                #pragma unroll
                for (int di = 0; di < 4; ++di)
                    acc_o[mi][di] = mfma16(pa[mi], vb[ks][di], acc_o[mi][di]);
            __builtin_amdgcn_s_setprio(0);
        }
        if (it <= 13)      { WAIT_VM4(); BAR(); SFENCE(); }   // next tile resident
        else if (it == 14) { WAIT_VM0(); BAR(); SFENCE(); }
    }

    // ---- reduce l across g4 groups (lane holds quarter-sum for its n col)
    #pragma unroll
    for (int mi = 0; mi < 2; ++mi) {
        float l = l_run[mi];
        l += __shfl_xor(l, 16);
        l += __shfl_xor(l, 32);
        l_run[mi] = 1.f / l;
    }
    // ---- normalize + write aout[b][n][c] bf16 (acc rows n = g4*4+r)
    #pragma unroll
    for (int mi = 0; mi < 2; ++mi) {
        float inv[4];
        #pragma unroll
        for (int r = 0; r < 4; ++r)
            inv[r] = __shfl(l_run[mi], g4 * 4 + r);   // src lane's lr == g4*4+r
        #pragma unroll
        for (int di = 0; di < 4; ++di)
            #pragma unroll
            for (int r = 0; r < 4; ++r) {
                int n = qtile * 128 + w * 32 + mi * 16 + g4 * 4 + r;
                int c = h * 64 + di * 16 + lr;
                aout[((size_t)b * 1024 + n) * 512 + c] = f2bf(acc_o[mi][di][r] * inv[r]);
            }
    }
}

// ---------------------------------------------------------------------------
// GroupNorm apply + affine + residual: reads bf16 proj + fp32 x, writes fp32
// out. Stats from 16 float2 partials per (b,g) (proj GEMM epilogue).
// ---------------------------------------------------------------------------
__global__ __launch_bounds__(256)
void gn_apply_kernel(const unsigned short* __restrict__ pb,
                     const float* __restrict__ partial, const float* __restrict__ x,
                     const float* __restrict__ gamma, const float* __restrict__ beta,
                     float* __restrict__ out) {
    const int qtr = blockIdx.x;   // 16: 4 channels each
    const int g = blockIdx.y;
    const int b = blockIdx.z;
    const int t = threadIdx.x;
    const float2* pp = (const float2*)partial + (size_t)(b * 8 + g) * 16;
    float sum = 0.f, sq = 0.f;
    #pragma unroll
    for (int s = 0; s < 16; ++s) { sum += pp[s].x; sq += pp[s].y; }
    const float mean = sum * (1.f / 65536.f);
    const float var  = sq * (1.f / 65536.f) - mean * mean;
    const float rstd = rsqrtf(var + GN_EPS);
    #pragma unroll
    for (int j = 0; j < 2; ++j) {
        const int c = g * 64 + qtr * 4 + j * 2 + (t >> 7);
        const float gm = gamma[c] * rstd, bt = beta[c];
        const size_t base = ((size_t)b * 512 + c) * 1024 + (t & 127) * 8;
        s16x8 pv = *(const s16x8_a*)(pb + base);
        float4 xa = *(const float4*)(x + base);
        float4 xb = *(const float4*)(x + base + 4);
        float4 ra, rb;
        ra.x = (__builtin_bit_cast(float, ((unsigned)(unsigned short)pv[0]) << 16) - mean) * gm + bt + xa.x;
        ra.y = (__builtin_bit_cast(float, ((unsigned)(unsigned short)pv[1]) << 16) - mean) * gm + bt + xa.y;
        ra.z = (__builtin_bit_cast(float, ((unsigned)(unsigned short)pv[2]) << 16) - mean) * gm + bt + xa.z;
        ra.w = (__builtin_bit_cast(float, ((unsigned)(unsigned short)pv[3]) << 16) - mean) * gm + bt + xa.w;
        rb.x = (__builtin_bit_cast(float, ((unsigned)(unsigned short)pv[4]) << 16) - mean) * gm + bt + xb.x;
        rb.y = (__builtin_bit_cast(float, ((unsigned)(unsigned short)pv[5]) << 16) - mean) * gm + bt + xb.y;
        rb.z = (__builtin_bit_cast(float, ((unsigned)(unsigned short)pv[6]) << 16) - mean) * gm + bt + xb.z;
        rb.w = (__builtin_bit_cast(float, ((unsigned)(unsigned short)pv[7]) << 16) - mean) * gm + bt + xb.w;
        *(float4*)(out + base) = ra;
        *(float4*)(out + base + 4) = rb;
    }
}

// ---------------------------------------------------------------------------
extern "C" void kernel_launch(void* const* d_in, const int* in_sizes, int n_in,
                              void* d_out, int out_size, void* d_ws, size_t ws_size,
                              hipStream_t stream) {
    (void)in_sizes; (void)n_in; (void)out_size; (void)ws_size;
    const float* x      = (const float*)d_in[0];
    const float* w_qkv  = (const float*)d_in[1];
    const float* w_proj = (const float*)d_in[2];
    const float* gamma  = (const float*)d_in[3];
    const float* beta   = (const float*)d_in[4];
    float* out = (float*)d_out;

    // workspace layout (ushort units), ~53 MB of 256 MB
    unsigned short* qtb  = (unsigned short*)d_ws;         // [8][8][1024][64]
    unsigned short* ktb  = qtb  + 4194304;                // [8][8][1024][64]
    unsigned short* vtb  = ktb  + 4194304;                // [8][8][16][64][64] tiled
    unsigned short* aoutb= vtb  + 4194304;                // [8][1024][512]
    unsigned short* xtb  = aoutb+ 4194304;                // [8][1024][512]
    unsigned short* pbf  = xtb  + 4194304;                // [8][512][1024] bf16 proj
    unsigned short* wqb  = pbf  + 4194304;                // [1536][512]
    unsigned short* wpb  = wqb  + 786432;                 // [512][512]
    float* partial = (float*)(wpb + 262144);              // [64][16] float2

    // 1) fused prep: xT + weight converts
    prep_kernel<<<2048, 256, 0, stream>>>(x, w_qkv, w_proj, xtb, wqb, wpb);
    // 2) QKV GEMM -> qt/kt (q scaled for exp2) + tiled vt
    mm_kernel<1536, 1><<<768, 256, 0, stream>>>(wqb, xtb, nullptr, qtb, ktb, vtb, nullptr);
    // 3) attention -> aout[b][n][c] bf16
    attn_kernel<<<512, 256, 0, stream>>>(qtb, ktb, vtb, aoutb);
    // 4) proj GEMM -> bf16 [b][c][n] + fused GN partial stats
    mm_kernel<512, 2><<<256, 256, 0, stream>>>(wpb, aoutb, pbf, nullptr, nullptr, nullptr, partial);
    // 5) GroupNorm apply (+affine +residual) -> fp32 out
    gn_apply_kernel<<<dim3(16, 8, B_DIM), 256, 0, stream>>>(pbf, partial, x, gamma, beta, out);
}

// Round 17
// 76.149 us; speedup vs baseline: 1.4580x; 1.0221x over previous
//
#include <hip/hip_runtime.h>

#define B_DIM 8
#define GN_EPS 1e-5f

typedef short s16x8 __attribute__((ext_vector_type(8)));
typedef float f32x4 __attribute__((ext_vector_type(4)));
typedef unsigned int u32x2 __attribute__((ext_vector_type(2)));
typedef s16x8 s16x8_a __attribute__((may_alias));
typedef u32x2 u32x2_a __attribute__((may_alias));

// fp32 -> bf16 bits, round-to-nearest-even
__device__ inline unsigned short f2bf(float f) {
    unsigned u = __builtin_bit_cast(unsigned, f);
    u += 0x7fffu + ((u >> 16) & 1u);
    return (unsigned short)(u >> 16);
}

// pack two fp32 -> two bf16 in one u32 (RNE), low half = lo
__device__ inline unsigned cvtpk(float lo, float hi) {
    unsigned r;
    asm("v_cvt_pk_bf16_f32 %0, %1, %2" : "=v"(r) : "v"(lo), "v"(hi));
    return r;
}

// D = A*B + C, 16x16x32 bf16 (A: row=lane&15,k=(lane>>4)*8+j; B: col=lane&15;
// C/D: col=lane&15,row=(lane>>4)*4+reg). Builtin -> hazard recognizer active.
__device__ inline f32x4 mfma16(s16x8 a, s16x8 b, f32x4 c) {
    return __builtin_amdgcn_mfma_f32_16x16x32_bf16(a, b, c, 0, 0, 0);
}

// async global->LDS, 16B per lane; lds dst must be wave-uniform base
__device__ inline void gload16(const unsigned short* g, unsigned short* l) {
    __builtin_amdgcn_global_load_lds(
        (const __attribute__((address_space(1))) unsigned int*)g,
        (__attribute__((address_space(3))) unsigned int*)l, 16, 0, 0);
}

// NOTE: counted-vmcnt asm is only sound when (a) the kernel has ZERO spill
// traffic (scratch ops count toward vmcnt) and (b) the wait depth covers a
// FULL future tile (vmcnt(4), triple-buffer). Mixed-depth contracts
// (vmcnt(2) over interleaved K/V streams) failed on hardware 3/3 (r9/r10/r13).
// Per-lane global K/V reads (no staging) passed but were 3.4x SLOWER (r15:
// L2 latency exposure, no async queue depth). setprio: neutral-to-negative
// (r16, lockstep schedule has no wave role diversity). This build (= r14)
// is the best measured configuration: 76.20 us, passed 4x.
#define WAIT_VM4() asm volatile("s_waitcnt vmcnt(4)" : : : "memory")
#define WAIT_VM0() asm volatile("s_waitcnt vmcnt(0)" : : : "memory")
#define BAR() __builtin_amdgcn_s_barrier()
// s_barrier is not a compiler memory fence; pin the schedule at it.
#define SFENCE() __builtin_amdgcn_sched_barrier(0)

// swizzled ushort index in a [rows][64] bf16 tile (128B rows): XOR 16B chunks
#define SWZ(r, c) ((r)*64 + ((c) ^ (((r)&7) << 3)))

// ---------------------------------------------------------------------------
// prep: fused {x transpose->bf16} + {w_qkv cvt} + {w_proj cvt}, one launch.
// blocks 0..1023: xT (16 ntile x 8 ctile x 8 b); 1024..1791: wq; 1792..2047: wp
// ---------------------------------------------------------------------------
__global__ __launch_bounds__(256)
void prep_kernel(const float* __restrict__ x, const float* __restrict__ wq,
                 const float* __restrict__ wp, unsigned short* __restrict__ xt,
                 unsigned short* __restrict__ wqb, unsigned short* __restrict__ wpb) {
    const int bid = blockIdx.x, t = threadIdx.x;
    __shared__ float ts[64][65];
    if (bid < 1024) {
        const int ntile = bid & 15, ctile = (bid >> 4) & 7, b = bid >> 7;
        const float* xp = x + ((size_t)b * 512 + ctile * 64) * 1024 + ntile * 64;
        #pragma unroll
        for (int i = 0; i < 16; ++i) {
            int f = i * 256 + t; int c = f >> 6, n = f & 63;
            ts[n][c] = xp[(size_t)c * 1024 + n];
        }
        __syncthreads();
        unsigned short* xo = xt + ((size_t)b * 1024 + ntile * 64) * 512 + ctile * 64;
        #pragma unroll
        for (int i = 0; i < 8; ++i) {
            int f = i * 512 + t * 2; int n = f >> 6, c = f & 63;
            unsigned lo = f2bf(ts[n][c]);
            unsigned hi = f2bf(ts[n][c + 1]);
            *(unsigned int*)&xo[(size_t)n * 512 + c] = lo | (hi << 16);
        }
    } else {
        const float4* src; unsigned short* dst; int idx;
        if (bid < 1792) { idx = (bid - 1024) * 256 + t; src = (const float4*)wq; dst = wqb; }
        else            { idx = (bid - 1792) * 256 + t; src = (const float4*)wp; dst = wpb; }
        float4 v = src[idx];
        ushort4 pk;
        pk.x = f2bf(v.x); pk.y = f2bf(v.y); pk.z = f2bf(v.z); pk.w = f2bf(v.w);
        *(ushort4*)&dst[(size_t)idx * 4] = pk;
    }
}

// ---------------------------------------------------------------------------
// GEMM Y[b][o][n] = sum_c W[o][c]*X[c][n]; A = Wb bf16 [O][512], B from
// Xt bf16 [b][n][512]. 128o x 128n tile, BK=32, 4 waves (2x2 of 64x64).
// K-loop: TRIPLE-buffered LDS, 2-deep prefetch, counted vmcnt(4) + raw
// s_barrier + sched_barrier(0) fence.
// MODE 1 (QKV): LDS-transpose epilogue -> qt/kt [b][h][n][64] (q scaled by
//   0.125*log2e), vt tiled [b][h][mtile][64 d][64 m]; all b64 stores.
// MODE 2 (proj): bf16 out [b][c][n] via same transpose + fused GN stats.
// ---------------------------------------------------------------------------
template<int O_DIM, int MODE>
__global__ __launch_bounds__(256)
void mm_kernel(const unsigned short* __restrict__ Wb,
               const unsigned short* __restrict__ Xt,
               unsigned short* __restrict__ proj_bf,
               unsigned short* __restrict__ qt,
               unsigned short* __restrict__ kt,
               unsigned short* __restrict__ vt,
               float* __restrict__ partial) {
    constexpr int OT = O_DIM / 128;
    const int bi = blockIdx.x;
    const int nt = bi & 7;             // same n-tile -> same XCD (L2 reuse of Xt)
    const int rest = bi >> 3;
    const int ot = rest % OT;
    const int b  = rest / OT;

    const int t = threadIdx.x;
    const int w = t >> 6, lid = t & 63, lr = lid & 15, g4 = lid >> 4;
    const int wr = w >> 1, wc = w & 1;

    // 3 staging bufs (8192 ushorts each: Ws[128][32] | Xs[128][32]);
    // epilogue reuses first 17408 as 4 per-wave 64x68 T tiles.
    __shared__ unsigned short lds[24576];

    const unsigned short* wsrc = Wb + ((size_t)(ot * 128 + w * 32 + (lid >> 2))) * 512 + (lid & 3) * 8;
    const unsigned short* xsrc = Xt + ((size_t)b * 1024 + nt * 128 + w * 32 + (lid >> 2)) * 512 + (lid & 3) * 8;
    const int woff0 = (w * 32) * 32;
    const int woff1 = (w * 32 + 16) * 32;

    const f32x4 Z4 = {0.f, 0.f, 0.f, 0.f};
    f32x4 acc[4][4];
    #pragma unroll
    for (int i = 0; i < 4; ++i)
        #pragma unroll
        for (int j = 0; j < 4; ++j) acc[i][j] = Z4;

    // prologue: stage K-tiles 0 and 1
    #pragma unroll
    for (int p = 0; p < 2; ++p) {
        unsigned short* nb = lds + p * 8192;
        const int k0 = p * 32;
        gload16(wsrc + k0, nb + woff0);
        gload16(wsrc + k0 + 16 * 512, nb + woff1);
        gload16(xsrc + k0, nb + 4096 + woff0);
        gload16(xsrc + k0 + 16 * 512, nb + 4096 + woff1);
    }
    WAIT_VM4(); BAR(); SFENCE();             // tile 0 resident (tile 1 in flight)

    #pragma unroll 1
    for (int it = 0; it < 16; ++it) {
        unsigned short* buf = lds + (it % 3) * 8192;
        if (it <= 13) {                      // 2-deep prefetch
            const int k2 = (it + 2) * 32;
            unsigned short* nb = lds + ((it + 2) % 3) * 8192;
            gload16(wsrc + k2, nb + woff0);
            gload16(wsrc + k2 + 16 * 512, nb + woff1);
            gload16(xsrc + k2, nb + 4096 + woff0);
            gload16(xsrc + k2 + 16 * 512, nb + 4096 + woff1);
        }
        s16x8 av[4], bv[4];
        #pragma unroll
        for (int mi = 0; mi < 4; ++mi)
            av[mi] = *(const s16x8*)&buf[(wr * 64 + mi * 16 + lr) * 32 + g4 * 8];
        #pragma unroll
        for (int nj = 0; nj < 4; ++nj)
            bv[nj] = *(const s16x8*)&buf[4096 + (wc * 64 + nj * 16 + lr) * 32 + g4 * 8];
        #pragma unroll
        for (int mi = 0; mi < 4; ++mi)
            #pragma unroll
            for (int nj = 0; nj < 4; ++nj)
                acc[mi][nj] = mfma16(av[mi], bv[nj], acc[mi][nj]);
        if (it <= 13)      { WAIT_VM4(); BAR(); SFENCE(); }   // next tile resident
        else if (it == 14) { WAIT_VM0(); BAR(); SFENCE(); }   // last tile resident
    }

    if (MODE == 2) {
        // fused GroupNorm partial stats over this wave's 64x64 quadrant
        // (entirely in group g = ot*2 + wr) — register-only, pre-barrier.
        float s1 = 0.f, s2 = 0.f;
        #pragma unroll
        for (int mi = 0; mi < 4; ++mi)
            #pragma unroll
            for (int nj = 0; nj < 4; ++nj)
                #pragma unroll
                for (int r = 0; r < 4; ++r) {
                    float v = acc[mi][nj][r];
                    s1 += v;
                    s2 += v * v;
                }
        #pragma unroll
        for (int off = 1; off <= 32; off <<= 1) {
            s1 += __shfl_xor(s1, off);
            s2 += __shfl_xor(s2, off);
        }
        if (lid == 0) {
            float2* pp = (float2*)partial + ((size_t)(b * 8 + ot * 2 + wr) * 16)
                         + nt * 2 + wc;
            *pp = make_float2(s1, s2);
        }
    }

    __syncthreads();                          // all waves done with staging LDS
    unsigned short* T = lds + w * 4352;       // per-wave 64x68 ushort
    const int obase = ot * 128 + wr * 64;
    const int j16 = lid & 15, r4 = lid >> 4;
    const size_t n0w = (size_t)nt * 128 + wc * 64;

    if (MODE == 1) {
        const int s = obase >> 9;             // 0=q 1=k 2=v
        const int h = (obase >> 6) & 7;
        const float scl = (s == 0) ? 0.18033688f : 1.0f;   // 0.125 * log2(e)
        #pragma unroll
        for (int mi = 0; mi < 4; ++mi)
            #pragma unroll
            for (int nj = 0; nj < 4; ++nj)
                #pragma unroll
                for (int r = 0; r < 4; ++r) {
                    int ol = mi * 16 + g4 * 4 + r, nl = nj * 16 + lr;
                    unsigned short v = f2bf(acc[mi][nj][r] * scl);
                    T[(s < 2) ? (nl * 68 + ol) : (ol * 68 + nl)] = v;
                }
        // q/k: [n][64 d]; vt tiled: [mtile][64 d][64 m] -> same base formula
        unsigned short* obuf = ((s == 0) ? qt : (s == 1) ? kt : vt)
                               + ((size_t)(b * 8 + h) * 1024 + n0w) * 64;
        #pragma unroll
        for (int p = 0; p < 16; ++p) {
            int rw = p * 4 + r4;
            u32x2 v = *(const u32x2_a*)&T[rw * 68 + 4 * j16];
            *(u32x2_a*)(obuf + rw * 64 + 4 * j16) = v;
        }
    } else {
        #pragma unroll
        for (int mi = 0; mi < 4; ++mi)
            #pragma unroll
            for (int nj = 0; nj < 4; ++nj)
                #pragma unroll
                for (int r = 0; r < 4; ++r)
                    T[(mi * 16 + g4 * 4 + r) * 68 + nj * 16 + lr] = f2bf(acc[mi][nj][r]);
        #pragma unroll
        for (int p = 0; p < 16; ++p) {
            int rw = p * 4 + r4;
            u32x2 v = *(const u32x2_a*)&T[rw * 68 + 4 * j16];
            *(u32x2_a*)(proj_bf + ((size_t)(b * 512 + obase + rw)) * 1024
                        + nt * 128 + wc * 64 + 4 * j16) = v;
        }
    }
}

// ---------------------------------------------------------------------------
// Flash attention, bf16 MFMA, static-max softmax. Block = (b,h,128-q-tile),
// 4 waves x 32 q-rows, grid 512. Q in registers. K/V TRIPLE-buffered in LDS
// with 2-deep prefetch + counted vmcnt(4) + raw barrier + sched fence.
// vt is tiled [mtile][64 d][64 m] -> every gload is one contiguous 1KB.
// Swapped QK^T -> packed cvt_pk b64 P-stores; l reduced once at the end.
// THE ONLY FAST+CORRECT PIPELINE FOUND (passes r7/r11/r12/r14).
// ---------------------------------------------------------------------------
__global__ __launch_bounds__(256)
void attn_kernel(const unsigned short* __restrict__ qt,
                 const unsigned short* __restrict__ kt,
                 const unsigned short* __restrict__ vt,
                 unsigned short* __restrict__ aout) {
    const int bi = blockIdx.x;
    const int h = bi & 7;               // all q-tiles of a head -> same XCD
    const int qtile = (bi >> 3) & 7;
    const int b = bi >> 6;

    const int t = threadIdx.x;
    const int w = t >> 6, lid = t & 63, lr = lid & 15, g4 = lid >> 4;
    const int rr = lid >> 3, cc = lid & 7;
    const int csw = (cc ^ rr) << 3;     // source pre-swizzle (ushort units)

    // K[3][4096] | V[3][4096] @12288 | P[128][64] @24576   (64KB)
    __shared__ unsigned short lds[32768];
    unsigned short* Ps = lds + 24576;

    const unsigned short* qbh = qt + ((size_t)b * 8 + h) * 65536;
    const unsigned short* kbh = kt + ((size_t)b * 8 + h) * 65536;
    const unsigned short* vbh = vt + ((size_t)b * 8 + h) * 65536;

    // ---- Q fragments straight into registers (B-operand: col=n, k=d)
    s16x8 qa[2][2];
    #pragma unroll
    for (int mi = 0; mi < 2; ++mi)
        #pragma unroll
        for (int ks = 0; ks < 2; ++ks)
            qa[mi][ks] = *(const s16x8*)(qbh +
                (size_t)(qtile * 128 + w * 32 + mi * 16 + lr) * 64 + ks * 32 + g4 * 8);

    // ---- prologue: stage tiles 0,1 (K and tiled-V share the address form)
    #pragma unroll
    for (int p = 0; p < 2; ++p) {
        unsigned short* Kd = lds + p * 4096;
        unsigned short* Vd = lds + 12288 + p * 4096;
        const int m = p * 64;
        #pragma unroll
        for (int i2 = 0; i2 < 2; ++i2) {
            gload16(kbh + (size_t)(m + w * 16 + i2 * 8 + rr) * 64 + csw,
                    Kd + (w * 16 + i2 * 8) * 64);
            gload16(vbh + (size_t)(m + w * 16 + i2 * 8 + rr) * 64 + csw,
                    Vd + (w * 16 + i2 * 8) * 64);
        }
    }
    WAIT_VM4(); BAR(); SFENCE();             // tile 0 resident

    const f32x4 Z4 = {0.f, 0.f, 0.f, 0.f};
    f32x4 acc_o[2][4];
    float l_run[2] = {0.f, 0.f};
    #pragma unroll
    for (int mi = 0; mi < 2; ++mi)
        #pragma unroll
        for (int di = 0; di < 4; ++di) acc_o[mi][di] = Z4;

    #pragma unroll 1
    for (int it = 0; it < 16; ++it) {
        unsigned short* Kc = lds + (it % 3) * 4096;
        unsigned short* Vc = lds + 12288 + (it % 3) * 4096;

        if (it <= 13) {                      // 2-deep prefetch
            const int m2 = (it + 2) * 64;
            unsigned short* Kd = lds + ((it + 2) % 3) * 4096;
            unsigned short* Vd = lds + 12288 + ((it + 2) % 3) * 4096;
            #pragma unroll
            for (int i2 = 0; i2 < 2; ++i2) {
                gload16(kbh + (size_t)(m2 + w * 16 + i2 * 8 + rr) * 64 + csw,
                        Kd + (w * 16 + i2 * 8) * 64);
                gload16(vbh + (size_t)(m2 + w * 16 + i2 * 8 + rr) * 64 + csw,
                        Vd + (w * 16 + i2 * 8) * 64);
            }
        }

        // ---- S^T: sc[mi][mj] = mfma(K, Q) -> row=m=mj*16+g4*4+r, col=n
        f32x4 sc[2][4];
        #pragma unroll
        for (int mi = 0; mi < 2; ++mi)
            #pragma unroll
            for (int mj = 0; mj < 4; ++mj) sc[mi][mj] = Z4;
        #pragma unroll
        for (int ks = 0; ks < 2; ++ks) {
            s16x8 kb[4];
            #pragma unroll
            for (int mj = 0; mj < 4; ++mj)
                kb[mj] = *(const s16x8*)&Kc[SWZ(mj * 16 + lr, ks * 32 + g4 * 8)];
            #pragma unroll
            for (int mi = 0; mi < 2; ++mi)
                #pragma unroll
                for (int mj = 0; mj < 4; ++mj)
                    sc[mi][mj] = mfma16(kb[mj], qa[mi][ks], sc[mi][mj]);
        }

        // ---- p = exp2(s) (log2e pre-folded), accumulate l, pack, store
        #pragma unroll
        for (int mi = 0; mi < 2; ++mi) {
            #pragma unroll
            for (int mj = 0; mj < 4; ++mj) {
                float p0 = __builtin_amdgcn_exp2f(sc[mi][mj][0]);
                float p1 = __builtin_amdgcn_exp2f(sc[mi][mj][1]);
                float p2 = __builtin_amdgcn_exp2f(sc[mi][mj][2]);
                float p3 = __builtin_amdgcn_exp2f(sc[mi][mj][3]);
                l_run[mi] += (p0 + p1) + (p2 + p3);
                u32x2 pk;
                pk.x = cvtpk(p0, p1);
                pk.y = cvtpk(p2, p3);
                *(u32x2_a*)&Ps[SWZ(w * 32 + mi * 16 + lr, mj * 16 + g4 * 4)] = pk;
            }
        }

        // ---- V fragments once per iter (register-resident across mi)
        s16x8 vb[2][4];
        #pragma unroll
        for (int ks = 0; ks < 2; ++ks)
            #pragma unroll
            for (int di = 0; di < 4; ++di)
                vb[ks][di] = *(const s16x8*)&Vc[SWZ(di * 16 + lr, ks * 32 + g4 * 8)];

        // ---- PV: acc_o[mi][di] += P[32n x 64m] * V^T[64m x 64d]
        #pragma unroll
        for (int ks = 0; ks < 2; ++ks) {
            s16x8 pa[2];
            #pragma unroll
            for (int mi = 0; mi < 2; ++mi)
                pa[mi] = *(const s16x8_a*)&Ps[SWZ(w * 32 + mi * 16 + lr, ks * 32 + g4 * 8)];
            #pragma unroll
            for (int mi = 0; mi < 2; ++mi)
                #pragma unroll
                for (int di = 0; di < 4; ++di)
                    acc_o[mi][di] = mfma16(pa[mi], vb[ks][di], acc_o[mi][di]);
        }
        if (it <= 13)      { WAIT_VM4(); BAR(); SFENCE(); }   // next tile resident
        else if (it == 14) { WAIT_VM0(); BAR(); SFENCE(); }
    }

    // ---- reduce l across g4 groups (lane holds quarter-sum for its n col)
    #pragma unroll
    for (int mi = 0; mi < 2; ++mi) {
        float l = l_run[mi];
        l += __shfl_xor(l, 16);
        l += __shfl_xor(l, 32);
        l_run[mi] = 1.f / l;
    }
    // ---- normalize + write aout[b][n][c] bf16 (acc rows n = g4*4+r)
    #pragma unroll
    for (int mi = 0; mi < 2; ++mi) {
        float inv[4];
        #pragma unroll
        for (int r = 0; r < 4; ++r)
            inv[r] = __shfl(l_run[mi], g4 * 4 + r);   // src lane's lr == g4*4+r
        #pragma unroll
        for (int di = 0; di < 4; ++di)
            #pragma unroll
            for (int r = 0; r < 4; ++r) {
                int n = qtile * 128 + w * 32 + mi * 16 + g4 * 4 + r;
                int c = h * 64 + di * 16 + lr;
                aout[((size_t)b * 1024 + n) * 512 + c] = f2bf(acc_o[mi][di][r] * inv[r]);
            }
    }
}

// ---------------------------------------------------------------------------
// GroupNorm apply + affine + residual: reads bf16 proj + fp32 x, writes fp32
// out. Stats from 16 float2 partials per (b,g) (proj GEMM epilogue).
// ---------------------------------------------------------------------------
__global__ __launch_bounds__(256)
void gn_apply_kernel(const unsigned short* __restrict__ pb,
                     const float* __restrict__ partial, const float* __restrict__ x,
                     const float* __restrict__ gamma, const float* __restrict__ beta,
                     float* __restrict__ out) {
    const int qtr = blockIdx.x;   // 16: 4 channels each
    const int g = blockIdx.y;
    const int b = blockIdx.z;
    const int t = threadIdx.x;
    const float2* pp = (const float2*)partial + (size_t)(b * 8 + g) * 16;
    float sum = 0.f, sq = 0.f;
    #pragma unroll
    for (int s = 0; s < 16; ++s) { sum += pp[s].x; sq += pp[s].y; }
    const float mean = sum * (1.f / 65536.f);
    const float var  = sq * (1.f / 65536.f) - mean * mean;
    const float rstd = rsqrtf(var + GN_EPS);
    #pragma unroll
    for (int j = 0; j < 2; ++j) {
        const int c = g * 64 + qtr * 4 + j * 2 + (t >> 7);
        const float gm = gamma[c] * rstd, bt = beta[c];
        const size_t base = ((size_t)b * 512 + c) * 1024 + (t & 127) * 8;
        s16x8 pv = *(const s16x8_a*)(pb + base);
        float4 xa = *(const float4*)(x + base);
        float4 xb = *(const float4*)(x + base + 4);
        float4 ra, rb;
        ra.x = (__builtin_bit_cast(float, ((unsigned)(unsigned short)pv[0]) << 16) - mean) * gm + bt + xa.x;
        ra.y = (__builtin_bit_cast(float, ((unsigned)(unsigned short)pv[1]) << 16) - mean) * gm + bt + xa.y;
        ra.z = (__builtin_bit_cast(float, ((unsigned)(unsigned short)pv[2]) << 16) - mean) * gm + bt + xa.z;
        ra.w = (__builtin_bit_cast(float, ((unsigned)(unsigned short)pv[3]) << 16) - mean) * gm + bt + xa.w;
        rb.x = (__builtin_bit_cast(float, ((unsigned)(unsigned short)pv[4]) << 16) - mean) * gm + bt + xb.x;
        rb.y = (__builtin_bit_cast(float, ((unsigned)(unsigned short)pv[5]) << 16) - mean) * gm + bt + xb.y;
        rb.z = (__builtin_bit_cast(float, ((unsigned)(unsigned short)pv[6]) << 16) - mean) * gm + bt + xb.z;
        rb.w = (__builtin_bit_cast(float, ((unsigned)(unsigned short)pv[7]) << 16) - mean) * gm + bt + xb.w;
        *(float4*)(out + base) = ra;
        *(float4*)(out + base + 4) = rb;
    }
}

// ---------------------------------------------------------------------------
extern "C" void kernel_launch(void* const* d_in, const int* in_sizes, int n_in,
                              void* d_out, int out_size, void* d_ws, size_t ws_size,
                              hipStream_t stream) {
    (void)in_sizes; (void)n_in; (void)out_size; (void)ws_size;
    const float* x      = (const float*)d_in[0];
    const float* w_qkv  = (const float*)d_in[1];
    const float* w_proj = (const float*)d_in[2];
    const float* gamma  = (const float*)d_in[3];
    const float* beta   = (const float*)d_in[4];
    float* out = (float*)d_out;

    // workspace layout (ushort units), ~53 MB of 256 MB
    unsigned short* qtb  = (unsigned short*)d_ws;         // [8][8][1024][64]
    unsigned short* ktb  = qtb  + 4194304;                // [8][8][1024][64]
    unsigned short* vtb  = ktb  + 4194304;                // [8][8][16][64][64] tiled
    unsigned short* aoutb= vtb  + 4194304;                // [8][1024][512]
    unsigned short* xtb  = aoutb+ 4194304;                // [8][1024][512]
    unsigned short* pbf  = xtb  + 4194304;                // [8][512][1024] bf16 proj
    unsigned short* wqb  = pbf  + 4194304;                // [1536][512]
    unsigned short* wpb  = wqb  + 786432;                 // [512][512]
    float* partial = (float*)(wpb + 262144);              // [64][16] float2

    // 1) fused prep: xT + weight converts
    prep_kernel<<<2048, 256, 0, stream>>>(x, w_qkv, w_proj, xtb, wqb, wpb);
    // 2) QKV GEMM -> qt/kt (q scaled for exp2) + tiled vt
    mm_kernel<1536, 1><<<768, 256, 0, stream>>>(wqb, xtb, nullptr, qtb, ktb, vtb, nullptr);
    // 3) attention -> aout[b][n][c] bf16
    attn_kernel<<<512, 256, 0, stream>>>(qtb, ktb, vtb, aoutb);
    // 4) proj GEMM -> bf16 [b][c][n] + fused GN partial stats
    mm_kernel<512, 2><<<256, 256, 0, stream>>>(wpb, aoutb, pbf, nullptr, nullptr, nullptr, partial);
    // 5) GroupNorm apply (+affine +residual) -> fp32 out
    gn_apply_kernel<<<dim3(16, 8, B_DIM), 256, 0, stream>>>(pbf, partial, x, gamma, beta, out);
}